// Round 8
// baseline (272.324 us; speedup 1.0000x reference)
//
#include <hip/hip_runtime.h>

// ScaledDotProductAttention: context = softmax(relu(Q K^T) @ R / 8) @ V
// B=8, N=2048, D=64. R = (1+e)/(1+exp(1-dist)), shared across batch.
// Fully fused: QK^T computed inside the flash kernel (no Ph materialization).
//
// ws layout (needs ~28.5 MB):
//   [0,  8MB)  RhT : fp16 R^T, [j][m]
//   [8, 10MB)  VhT : fp16 V^T, [B][64][N]
//   [10,12MB)  Kh  : fp16 K,   [B][N][64]
//   [12,28MB)  Op  : fp16 partial O, [1024 wg][128][64]
//   [28MB,..)  mp, lp : fp32 partial rowmax/rowsum, [1024][128] each

typedef _Float16 f16;
typedef _Float16 f16x8 __attribute__((ext_vector_type(8)));
typedef float    f32x4 __attribute__((ext_vector_type(4)));

#define AS1C(p) ((const __attribute__((address_space(1))) void*)(p))
#define AS3(p)  ((__attribute__((address_space(3))) void*)(p))

__device__ __forceinline__ f16x8 cvt_f16x8(float4 a, float4 b){
  f16x8 v;
  v[0]=(f16)a.x; v[1]=(f16)a.y; v[2]=(f16)a.z; v[3]=(f16)a.w;
  v[4]=(f16)b.x; v[5]=(f16)b.y; v[6]=(f16)b.z; v[7]=(f16)b.w;
  return v;
}

// ---------------- kernel 0a: RhT[j][m] = rescale(dist[m][j]) in fp16 -------
__global__ void k_rescaleT(const float* __restrict__ Dm, f16* __restrict__ RhT){
  __shared__ f16 tl[64][65];
  const int k0 = blockIdx.x*64, m0 = blockIdx.y*64;
  const int t = threadIdx.x, c = t & 63, g = t >> 6;
#pragma unroll
  for (int i=0;i<16;++i){
    int k = g*16 + i;
    float d = Dm[(size_t)(k0 + k)*2048 + m0 + c];
    tl[k][c] = (f16)(3.7182818284590452f / (1.0f + __expf(1.0f - d)));
  }
  __syncthreads();
#pragma unroll
  for (int i=0;i<16;++i){
    int m = g*16 + i;
    RhT[(size_t)(m0 + m)*2048 + k0 + c] = tl[c][m];
  }
}

// ---------------- kernel 0b: VhT[b][d][m] = V[b][m][d] in fp16 -------------
__global__ void k_vT(const float* __restrict__ V, f16* __restrict__ VhT){
  __shared__ f16 tl[64][65];
  const int b = blockIdx.y, m0 = blockIdx.x*64;
  const int t = threadIdx.x, c = t & 63, g = t >> 6;
#pragma unroll
  for (int i=0;i<16;++i){
    int m = g*16 + i;
    tl[m][c] = (f16)V[((size_t)b*2048 + m0 + m)*64 + c];
  }
  __syncthreads();
#pragma unroll
  for (int i=0;i<16;++i){
    int d = g*16 + i;
    VhT[((size_t)b*64 + d)*2048 + m0 + c] = tl[c][d];
  }
}

// ---------------- kernel 0c: Kh = f16(K), same layout ----------------------
__global__ void k_cvtK(const float* __restrict__ K, f16* __restrict__ Kh){
  size_t i = ((size_t)blockIdx.x*256 + threadIdx.x)*8;
  *(f16x8*)(Kh + i) = cvt_f16x8(*(const float4*)(K+i), *(const float4*)(K+i+4));
}

// ---------------- kernel 1: fused flash attention --------------------------
// Grid 1024 = 16 nb x 8 b x 8 jq; jq = bid&7 == XCD id -> 1 MB R-slice per
// XCD stays L2-resident. Per WG (256 thr): 128 Q-rows x 256 j-cols.
// Per m-chunk(32): stage K-chunk (4 KB DMA, 2 ahead) + R-chunk (16 KB DMA,
// 1 ahead); wave w computes P rows 32w..+31 of the chunk (8 MFMA from
// register-resident Q-frags) and ds_writes them into Pbuf in swizzled
// A-layout; S-loop consumes Pbuf/Rbuf as before (wave tile 128x64).
// El (64x264) aliases the dead staging buffers during softmax/E@V.
// LDS 62464 B -> 2 WGs/CU.
__launch_bounds__(256, 2)
__global__ void k_attn(const float* __restrict__ Q, const f16* __restrict__ Kh,
                       const f16* __restrict__ RhT, const f16* __restrict__ VhT,
                       f16* __restrict__ Op, float* __restrict__ mp,
                       float* __restrict__ lp){
  __shared__ char smem[62464];
  f16*  Pbuf = (f16*)smem;                      // [2][128][32] = 16384 B
  f16*  Kbuf = (f16*)(smem + 16384);            // [2][32][64]  =  8192 B
  f16*  Rbuf = (f16*)(smem + 24576);            // [2][256][32] = 32768 B
  f16*  El   = (f16*)smem;                      // [64][264] = 33792 B (alias)
  float* stat_max = (float*)(smem + 57344);     // [128][4]
  float* stat_sum = (float*)(smem + 59392);     // [128][4]
  float* mrow = (float*)(smem + 61440);         // [128]
  float* lrow = (float*)(smem + 61952);         // [128]

  const int t = threadIdx.x, w = t>>6, l = t&63, lr = l&15, q = l>>4;
  const int bid = blockIdx.x;
  const int jq = bid & 7, nbb = bid >> 3, b = nbb & 7, nb = nbb >> 3;
  const int n0 = nb*128, jg = jq*256;
  const int wc = w*64;

  const float* Qb = Q   + ((size_t)b*2048 + n0)*64;
  const f16*  Khb = Kh  + (size_t)b*2048*64;
  const f16*  Vb  = VhT + (size_t)b*64*2048;

  if (t < 128){ mrow[t] = -1e30f; lrow[t] = 0.0f; }

  // Q-frags in registers: wave w produces P rows 32w..32w+31
  f16x8 qf[2][2];
#pragma unroll
  for (int a=0;a<2;++a)
#pragma unroll
    for (int dc=0;dc<2;++dc){
      const float* p = Qb + (size_t)(32*w + 16*a + lr)*64 + dc*32 + q*8;
      qf[a][dc] = cvt_f16x8(*(const float4*)p, *(const float4*)(p+4));
    }

  f32x4 Oacc[2][2][2] = {};
  const int swz  = (lr>>1)&3;                   // S-loop read swizzle
  const int kswz = lr&7;                        // K-buf read swizzle

  auto stageK = [&](int kc){
    const int cb = kc & 1;
    int row = t>>3, g = t&7;
    int gs = (g ^ (row&7))*8;
    __builtin_amdgcn_global_load_lds(AS1C(Khb + (size_t)(kc*32 + row)*64 + gs),
                                     AS3(Kbuf + cb*2048 + w*512), 16, 0, 0);
  };
  auto stageR = [&](int kc){
    const int cb = kc & 1, k0 = kc*32;
#pragma unroll
    for (int i=0;i<4;++i){
      int slot = i*256 + t, row = slot>>2, g = slot&3;
      int gs = (g ^ ((row>>1)&3))*8;
      __builtin_amdgcn_global_load_lds(AS1C(RhT + (size_t)(jg + row)*2048 + k0 + gs),
                                       AS3(Rbuf + cb*8192 + i*2048 + w*512), 16, 0, 0);
    }
  };
  auto computeP = [&](int kc){
    const int cb = kc & 1;
    const f16* Kb = Kbuf + cb*2048;
    f16x8 bf[2][2];
#pragma unroll
    for (int bb=0;bb<2;++bb)
#pragma unroll
      for (int dc=0;dc<2;++dc)
        bf[bb][dc] = *(const f16x8*)(Kb + (16*bb + lr)*64 + ((dc*4 + q) ^ kswz)*8);
    f32x4 pa[2][2] = {};
#pragma unroll
    for (int dc=0;dc<2;++dc)
#pragma unroll
      for (int a=0;a<2;++a)
#pragma unroll
        for (int bb=0;bb<2;++bb)
          pa[a][bb] = __builtin_amdgcn_mfma_f32_16x16x32_f16(qf[a][dc], bf[bb][dc], pa[a][bb], 0,0,0);
    f16* Pw = Pbuf + cb*4096;
#pragma unroll
    for (int a=0;a<2;++a)
#pragma unroll
      for (int bb=0;bb<2;++bb)
#pragma unroll
        for (int r=0;r<4;++r){
          int row = 32*w + 16*a + 4*q + r;
          int m   = 16*bb + lr;
          Pw[row*32 + ((m>>3) ^ ((row>>1)&3))*8 + (m&7)] =
              (f16)(fmaxf(pa[a][bb][r], 0.f)*0.125f);
        }
  };

  // prologue: K[0] staged -> P[0] computed; R[0], K[1] in flight
  stageK(0);
  __syncthreads();
  stageR(0); stageK(1);
  computeP(0);

  f32x4 acc[8][4] = {};
#pragma unroll 2
  for (int kc = 0; kc < 64; ++kc){
    __syncthreads();                            // R[kc], P[kc], K[kc+1] ready
    if (kc < 63) stageR(kc+1);
    if (kc < 62) stageK(kc+2);
    if (kc < 63) computeP(kc+1);
    const int cb = kc & 1;
    const f16* Pb = Pbuf + cb*4096;
    const f16* Rb = Rbuf + cb*8192;
    f16x8 bf2[4];
#pragma unroll
    for (int tj=0;tj<4;++tj)
      bf2[tj] = *(const f16x8*)(Rb + (wc + 16*tj + lr)*32 + (q ^ swz)*8);
#pragma unroll
    for (int ti=0;ti<8;++ti){
      f16x8 af = *(const f16x8*)(Pb + (16*ti + lr)*32 + (q ^ swz)*8);
#pragma unroll
      for (int tj=0;tj<4;++tj)
        acc[ti][tj] = __builtin_amdgcn_mfma_f32_16x16x32_f16(af, bf2[tj], acc[ti][tj], 0,0,0);
    }
  }

  // ---- softmax + E@V in two 64-row passes (El aliases staging bufs) ----
#pragma unroll
  for (int p=0;p<2;++p){
    float pm[4][4];
#pragma unroll
    for (int ti=0;ti<4;++ti)
#pragma unroll
      for (int r=0;r<4;++r)
        pm[ti][r] = fmaxf(fmaxf(acc[4*p+ti][0][r], acc[4*p+ti][1][r]),
                          fmaxf(acc[4*p+ti][2][r], acc[4*p+ti][3][r]));
#pragma unroll
    for (int mm=1;mm<16;mm<<=1)
#pragma unroll
      for (int ti=0;ti<4;++ti)
#pragma unroll
        for (int r=0;r<4;++r)
          pm[ti][r] = fmaxf(pm[ti][r], __shfl_xor(pm[ti][r], mm));
    if (lr == 0)
#pragma unroll
      for (int ti=0;ti<4;++ti)
#pragma unroll
        for (int r=0;r<4;++r)
          stat_max[(64*p + 16*ti + 4*q + r)*4 + w] = pm[ti][r];
    __syncthreads();                            // B1: maxima visible; staging dead

    float Mn[4][4], ps[4][4], al[2][4];
#pragma unroll
    for (int ti=0;ti<4;++ti)
#pragma unroll
      for (int r=0;r<4;++r){
        int row = 64*p + 16*ti + 4*q + r;
        float4 s4 = *(const float4*)&stat_max[row*4];
        float tm = fmaxf(fmaxf(s4.x,s4.y), fmaxf(s4.z,s4.w));
        float mo = mrow[row];
        float M  = fmaxf(mo, tm);
        Mn[ti][r] = M;
        ps[ti][r] = 0.f;
        if ((ti>>1) == (w&1)) al[ti&1][r] = __expf(mo - M);
      }
#pragma unroll
    for (int ti=0;ti<4;++ti)
#pragma unroll
      for (int tj=0;tj<4;++tj)
#pragma unroll
        for (int r=0;r<4;++r){
          float e = __expf(acc[4*p+ti][tj][r] - Mn[ti][r]);
          ps[ti][r] += e;
          El[(16*ti + 4*q + r)*264 + wc + 16*tj + lr] = (f16)e;
        }
#pragma unroll
    for (int mm=1;mm<16;mm<<=1)
#pragma unroll
      for (int ti=0;ti<4;++ti)
#pragma unroll
        for (int r=0;r<4;++r)
          ps[ti][r] += __shfl_xor(ps[ti][r], mm);
    if (lr == 0)
#pragma unroll
      for (int ti=0;ti<4;++ti)
#pragma unroll
        for (int r=0;r<4;++r)
          stat_sum[(64*p + 16*ti + 4*q + r)*4 + w] = ps[ti][r];
#pragma unroll
    for (int a=0;a<2;++a)
#pragma unroll
      for (int bb=0;bb<2;++bb)
#pragma unroll
        for (int r=0;r<4;++r)
          Oacc[p][a][bb][r] *= al[a][r];        // rescale running O
    __syncthreads();                            // B2: El + stat_sum visible

    if (t < 64){
      int row = 64*p + t;
      float m_o = mrow[row], tm = -1e30f, s4 = 0.f;
#pragma unroll
      for (int i=0;i<4;++i){ tm = fmaxf(tm, stat_max[row*4+i]); s4 += stat_sum[row*4+i]; }
      float M = fmaxf(m_o, tm);
      lrow[row] = lrow[row]*__expf(m_o - M) + s4;
      mrow[row] = M;
    }

    // ---- E @ V : O[pass rows][cols] += E[64][256] * V[256][64]
    const int erb = 32*(w&1), vcb = 32*(w>>1);
#pragma unroll
    for (int ks=0; ks<8; ++ks){
      f16x8 ae[2], bv[2];
#pragma unroll
      for (int a=0;a<2;++a)
        ae[a] = *(const f16x8*)(El + (erb + 16*a + lr)*264 + ks*32 + q*8);
#pragma unroll
      for (int bb=0;bb<2;++bb)
        bv[bb] = *(const f16x8*)(Vb + (size_t)(vcb + 16*bb + lr)*2048 + jg + ks*32 + q*8);
#pragma unroll
      for (int a=0;a<2;++a)
#pragma unroll
        for (int bb=0;bb<2;++bb)
          Oacc[p][a][bb] = __builtin_amdgcn_mfma_f32_16x16x32_f16(ae[a], bv[bb], Oacc[p][a][bb], 0,0,0);
    }
    __syncthreads();                            // B3: El reads done
  }

  // final mrow/lrow visible (B3 above)
#pragma unroll
  for (int p=0;p<2;++p)
#pragma unroll
    for (int a=0;a<2;++a)
#pragma unroll
      for (int bb=0;bb<2;++bb)
#pragma unroll
        for (int r=0;r<4;++r){
          int row = 64*p + 32*(w&1) + 16*a + 4*q + r;
          int col = 32*(w>>1) + 16*bb + lr;
          Op[((size_t)bid*128 + row)*64 + col] = (f16)Oacc[p][a][bb][r];
        }
  if (t < 128){ mp[bid*128 + t] = mrow[t]; lp[bid*128 + t] = lrow[t]; }
}

// ---------------- kernel 2: combine the 8 j-slice partials -----------------
__global__ void k_comb(const f16* __restrict__ Op, const float* __restrict__ mp,
                       const float* __restrict__ lp, float* __restrict__ out){
  const int rb = blockIdx.x;                    // 0..127 = nb*8 + b
  const int b = rb & 7, nb = rb >> 3;
  const int bid0 = rb << 3;
  const int t = threadIdx.x;
  const int row = t >> 1, half = t & 1;

  float m_[8], a_[8];
  float M = -1e30f, den = 0.f;
#pragma unroll
  for (int i=0;i<8;++i){ m_[i] = mp[(bid0+i)*128 + row]; M = fmaxf(M, m_[i]); }
#pragma unroll
  for (int i=0;i<8;++i){ a_[i] = __expf(m_[i] - M); den += a_[i]*lp[(bid0+i)*128 + row]; }
  float inv = 1.0f / den;

#pragma unroll
  for (int g=0;g<4;++g){
    int c0 = half*32 + g*8;
    float o[8] = {};
#pragma unroll
    for (int i=0;i<8;++i){
      f16x8 v = *(const f16x8*)(Op + ((size_t)(bid0+i)*128 + row)*64 + c0);
#pragma unroll
      for (int e=0;e<8;++e) o[e] += a_[i]*(float)v[e];
    }
    float4 o0, o1;
    o0.x=o[0]*inv; o0.y=o[1]*inv; o0.z=o[2]*inv; o0.w=o[3]*inv;
    o1.x=o[4]*inv; o1.y=o[5]*inv; o1.z=o[6]*inv; o1.w=o[7]*inv;
    float* dst = out + ((size_t)b*2048 + nb*128 + row)*64 + c0;
    *(float4*)dst = o0;
    *(float4*)(dst+4) = o1;
  }
}

extern "C" void kernel_launch(void* const* d_in, const int* in_sizes, int n_in,
                              void* d_out, int out_size, void* d_ws, size_t ws_size,
                              hipStream_t stream){
  (void)in_sizes; (void)n_in; (void)out_size; (void)ws_size;
  const float* Q  = (const float*)d_in[0];
  const float* K  = (const float*)d_in[1];
  const float* V  = (const float*)d_in[2];
  const float* Dm = (const float*)d_in[3];
  float* out = (float*)d_out;
  char* ws = (char*)d_ws;
  f16* RhT = (f16*)ws;                                   //  8 MB
  f16* VhT = (f16*)(ws + (size_t) 8*1024*1024);          //  2 MB
  f16* Kh  = (f16*)(ws + (size_t)10*1024*1024);          //  2 MB
  f16* Op  = (f16*)(ws + (size_t)12*1024*1024);          // 16 MB (1024*128*64 f16)
  float* mpp = (float*)(ws + (size_t)28*1024*1024);      // 512 KB
  float* lpp = mpp + 1024*128;                           // 512 KB

  k_rescaleT<<<dim3(32,32), 256, 0, stream>>>(Dm, RhT);
  k_vT      <<<dim3(32,8),  256, 0, stream>>>(V, VhT);
  k_cvtK    <<<dim3(512),   256, 0, stream>>>(K, Kh);
  k_attn    <<<dim3(1024),  256, 0, stream>>>(Q, Kh, RhT, VhT, Op, mpp, lpp);
  k_comb    <<<dim3(128),   256, 0, stream>>>(Op, mpp, lpp, out);
}

// Round 9
// 249.740 us; speedup vs baseline: 1.0904x; 1.0904x over previous
//
#include <hip/hip_runtime.h>

// ScaledDotProductAttention: context = softmax(relu(Q K^T) @ R / 8) @ V
// B=8, N=2048, D=64. R = (1+e)/(1+exp(1-dist)), shared across batch.
//
// ws layout (needs ~91.5 MB):
//   [0,   64MB)  Ph  : fp16 relu(QK^T)*0.125, [B][N][N]
//   [64MB,72MB)  RhT : fp16 R^T, [j][m]
//   [72MB,74MB)  VhT : fp16 V^T, [B][64][N]
//   [74MB,90MB)  Op  : fp16 partial O, [1024 wg][128][64]
//   [90MB,...)   mp, lp : fp32 partial rowmax/rowsum, [1024][128] each

typedef _Float16 f16;
typedef _Float16 f16x8 __attribute__((ext_vector_type(8)));
typedef float    f32x4 __attribute__((ext_vector_type(4)));

#define AS1C(p) ((const __attribute__((address_space(1))) void*)(p))
#define AS3(p)  ((__attribute__((address_space(3))) void*)(p))

__device__ __forceinline__ f16x8 cvt_f16x8(float4 a, float4 b){
  f16x8 v;
  v[0]=(f16)a.x; v[1]=(f16)a.y; v[2]=(f16)a.z; v[3]=(f16)a.w;
  v[4]=(f16)b.x; v[5]=(f16)b.y; v[6]=(f16)b.z; v[7]=(f16)b.w;
  return v;
}

// ---------------- kernel 1: fused prep + QK^T --------------------------------
// Flat grid 3328: [0,2048) QK tiles; [2048,3072) rescale-transpose tiles;
// [3072,3328) V-transpose tiles. One launch instead of three.
__launch_bounds__(256, 2)
__global__ void k_qk(const float* __restrict__ Q, const float* __restrict__ Km,
                     const float* __restrict__ V, const float* __restrict__ Dm,
                     f16* __restrict__ Ph, f16* __restrict__ RhT,
                     f16* __restrict__ VhT){
  __shared__ char shm[36864];
  const int bid = blockIdx.x;
  const int t = threadIdx.x;

  if (bid >= 2048){
    f16* tl = (f16*)shm;                         // [64][65]
    const int c = t & 63, g = t >> 6;
    if (bid < 3072){                             // RhT[j][m] = rescale(D[m][j])
      const int pid = bid - 2048;
      const int k0 = (pid & 31)*64, m0 = (pid >> 5)*64;
#pragma unroll
      for (int i=0;i<16;++i){
        int k = g*16 + i;
        float d = Dm[(size_t)(k0 + k)*2048 + m0 + c];
        tl[k*65 + c] = (f16)(3.7182818284590452f / (1.0f + __expf(1.0f - d)));
      }
      __syncthreads();
#pragma unroll
      for (int i=0;i<16;++i){
        int m = g*16 + i;
        RhT[(size_t)(m0 + m)*2048 + k0 + c] = tl[c*65 + m];
      }
    } else {                                     // VhT[b][d][m] = V[b][m][d]
      const int pid = bid - 3072;
      const int m0 = (pid & 31)*64, b = pid >> 5;
#pragma unroll
      for (int i=0;i<16;++i){
        int m = g*16 + i;
        tl[m*65 + c] = (f16)V[((size_t)b*2048 + m0 + m)*64 + c];
      }
      __syncthreads();
#pragma unroll
      for (int i=0;i<16;++i){
        int d = g*16 + i;
        VhT[((size_t)b*64 + d)*2048 + m0 + c] = tl[c*65 + d];
      }
    }
    return;
  }

  // ---- QK tile: Ph[128x128] = relu(Q K^T)*0.125 ----
  f16* Qt = (f16*)shm;            // [128][72]
  f16* Kt = (f16*)(shm + 18432);  // [128][72]
  f16* Tt = (f16*)shm;            // [128][136] aliases after compute

  const int w = t>>6, l = t&63, lr = l&15, q = l>>4;
  const int m0 = (bid & 15)*128, n0 = ((bid>>4) & 15)*128, b = bid >> 8;
  const int wr = (w>>1)*64, wc = (w&1)*64;
  const float* Qb = Q  + ((size_t)b*2048 + n0)*64;
  const float* Kb = Km + ((size_t)b*2048 + m0)*64;

  const int sr = t>>3, sc = t&7;
#pragma unroll
  for (int j=0;j<4;++j){
    int row = sr + 32*j;
    const float* p  = Qb + (size_t)row*64 + sc*8;
    *(f16x8*)(Qt + row*72 + sc*8) = cvt_f16x8(*(const float4*)p, *(const float4*)(p+4));
    const float* pk = Kb + (size_t)row*64 + sc*8;
    *(f16x8*)(Kt + row*72 + sc*8) = cvt_f16x8(*(const float4*)pk, *(const float4*)(pk+4));
  }
  __syncthreads();

  f32x4 acc[4][4] = {};
#pragma unroll
  for (int kc=0;kc<2;++kc){
    f16x8 af[4], bf[4];
#pragma unroll
    for (int ti=0;ti<4;++ti) af[ti] = *(const f16x8*)(Qt + (wr+16*ti+lr)*72 + kc*32 + q*8);
#pragma unroll
    for (int tj=0;tj<4;++tj) bf[tj] = *(const f16x8*)(Kt + (wc+16*tj+lr)*72 + kc*32 + q*8);
#pragma unroll
    for (int ti=0;ti<4;++ti)
#pragma unroll
      for (int tj=0;tj<4;++tj)
        acc[ti][tj] = __builtin_amdgcn_mfma_f32_16x16x32_f16(af[ti], bf[tj], acc[ti][tj], 0,0,0);
  }
  __syncthreads();
#pragma unroll
  for (int ti=0;ti<4;++ti)
#pragma unroll
    for (int tj=0;tj<4;++tj)
#pragma unroll
      for (int r=0;r<4;++r)
        Tt[(wr+16*ti+4*q+r)*136 + wc+16*tj+lr] = (f16)(fmaxf(acc[ti][tj][r],0.f)*0.125f);
  __syncthreads();
  const int g16 = t&15, r0 = t>>4;
#pragma unroll
  for (int j=0;j<8;++j){
    int row = r0 + 16*j;
    *(f16x8*)(Ph + ((size_t)b*2048 + n0 + row)*2048 + m0 + g16*8) =
        *(const f16x8*)(Tt + row*136 + g16*8);
  }
}

// ---------------- kernel 2: split-j flash attention over scores ------------
// Grid 1024 = 16 nb x 8 b x 8 jq; jq = bid&7 == XCD id -> 1 MB R-slice per
// XCD L2-resident. Per WG (256 thr): 128 Q-rows x ONE 256-col j-tile
// (nmt=1 -> no online-softmax state at all; k_comb merges slices).
// Per m-chunk(32): stage P 8K + R 16K via swizzled global_load_lds (dbuf).
// Wave tile 128x64. Post-S-loop the staging LDS is dead: El[64][264] and
// the stat arrays alias it. LDS = 49152 B exactly -> 3 WGs/CU if registers
// allow (acc AGPRs may cap at 2; this measures which).
__launch_bounds__(256, 2)
__global__ void k_attn(const f16* __restrict__ Ph, const f16* __restrict__ RhT,
                       const f16* __restrict__ VhT, f16* __restrict__ Op,
                       float* __restrict__ mp, float* __restrict__ lp){
  __shared__ char smem[49152];
  f16*  Pbuf = (f16*)smem;                      // [2][128][32] = 16384
  f16*  Rbuf = (f16*)(smem + 16384);            // [2][256][32] = 32768
  f16*  El   = (f16*)smem;                      // [64][264] = 33792 (alias)
  float* stat_max = (float*)(smem + 33792);     // [64][4] = 1024 (alias)
  float* stat_sum = (float*)(smem + 34816);     // [64][4] = 1024 (alias)

  const int t = threadIdx.x, w = t>>6, l = t&63, lr = l&15, q = l>>4;
  const int bid = blockIdx.x;
  const int jq = bid & 7, nbb = bid >> 3, b = nbb & 7, nb = nbb >> 3;
  const int n0 = nb*128, jg = jq*256;
  const int wc = w*64;

  const f16* Pblk = Ph  + ((size_t)b*2048 + n0)*2048;
  const f16* Vb   = VhT + (size_t)b*64*2048;

  // hoisted staging source pointers (advance by kc*32 halves each chunk)
  const f16* srcP[2];
  const f16* srcR[4];
#pragma unroll
  for (int i=0;i<2;++i){
    int slot = i*256 + t, row = slot>>2, g = slot&3;
    srcP[i] = Pblk + (size_t)row*2048 + (g ^ ((row>>1)&3))*8;
  }
#pragma unroll
  for (int i=0;i<4;++i){
    int slot = i*256 + t, row = slot>>2, g = slot&3;
    srcR[i] = RhT + (size_t)(jg + row)*2048 + (g ^ ((row>>1)&3))*8;
  }

  auto stage = [&](int kc){
    const int cb = kc & 1, k0 = kc*32;
#pragma unroll
    for (int i=0;i<2;++i)
      __builtin_amdgcn_global_load_lds(AS1C(srcP[i] + k0),
                                       AS3(Pbuf + cb*4096 + i*2048 + w*512), 16, 0, 0);
#pragma unroll
    for (int i=0;i<4;++i)
      __builtin_amdgcn_global_load_lds(AS1C(srcR[i] + k0),
                                       AS3(Rbuf + cb*8192 + i*2048 + w*512), 16, 0, 0);
  };

  const int swz = (lr>>1)&3;                    // read-side XOR swizzle
  f32x4 acc[8][4] = {};
  f32x4 Oacc[2][2][2] = {};

  stage(0);
#pragma unroll 2
  for (int kc = 0; kc < 64; ++kc){
    __syncthreads();                            // chunk kc staged
    if (kc < 63) stage(kc+1);
    const int cb = kc & 1;
    const f16* Pb = Pbuf + cb*4096;
    const f16* Rb = Rbuf + cb*8192;
    f16x8 bf[4];
#pragma unroll
    for (int tj=0;tj<4;++tj)
      bf[tj] = *(const f16x8*)(Rb + (wc + 16*tj + lr)*32 + (q ^ swz)*8);
#pragma unroll
    for (int ti=0;ti<8;++ti){
      f16x8 af = *(const f16x8*)(Pb + (16*ti + lr)*32 + (q ^ swz)*8);
#pragma unroll
      for (int tj=0;tj<4;++tj)
        acc[ti][tj] = __builtin_amdgcn_mfma_f32_16x16x32_f16(af, bf[tj], acc[ti][tj], 0,0,0);
    }
  }
  __syncthreads();                              // staging dead; aliases usable

  // ---- softmax + E@V in two 64-row passes (single epilogue, no running m/l)
#pragma unroll
  for (int p=0;p<2;++p){
    float pm[4][4];
#pragma unroll
    for (int ti=0;ti<4;++ti)
#pragma unroll
      for (int r=0;r<4;++r)
        pm[ti][r] = fmaxf(fmaxf(acc[4*p+ti][0][r], acc[4*p+ti][1][r]),
                          fmaxf(acc[4*p+ti][2][r], acc[4*p+ti][3][r]));
#pragma unroll
    for (int mm=1;mm<16;mm<<=1)
#pragma unroll
      for (int ti=0;ti<4;++ti)
#pragma unroll
        for (int r=0;r<4;++r)
          pm[ti][r] = fmaxf(pm[ti][r], __shfl_xor(pm[ti][r], mm));
    if (lr == 0)
#pragma unroll
      for (int ti=0;ti<4;++ti)
#pragma unroll
        for (int r=0;r<4;++r)
          stat_max[(16*ti + 4*q + r)*4 + w] = pm[ti][r];
    __syncthreads();                            // B1: per-wave maxima visible

    float Mn[4][4], ps[4][4];
#pragma unroll
    for (int ti=0;ti<4;++ti)
#pragma unroll
      for (int r=0;r<4;++r){
        int row = 16*ti + 4*q + r;
        float4 s4 = *(const float4*)&stat_max[row*4];
        Mn[ti][r] = fmaxf(fmaxf(s4.x,s4.y), fmaxf(s4.z,s4.w));
        ps[ti][r] = 0.f;
      }
#pragma unroll
    for (int ti=0;ti<4;++ti)
#pragma unroll
      for (int tj=0;tj<4;++tj)
#pragma unroll
        for (int r=0;r<4;++r){
          float e = __expf(acc[4*p+ti][tj][r] - Mn[ti][r]);
          ps[ti][r] += e;
          El[(16*ti + 4*q + r)*264 + wc + 16*tj + lr] = (f16)e;
        }
#pragma unroll
    for (int mm=1;mm<16;mm<<=1)
#pragma unroll
      for (int ti=0;ti<4;++ti)
#pragma unroll
        for (int r=0;r<4;++r)
          ps[ti][r] += __shfl_xor(ps[ti][r], mm);
    if (lr == 0)
#pragma unroll
      for (int ti=0;ti<4;++ti)
#pragma unroll
        for (int r=0;r<4;++r)
          stat_sum[(16*ti + 4*q + r)*4 + w] = ps[ti][r];
    __syncthreads();                            // B2: El + stat_sum visible

    if (w == 0 && lr == 0)                      // write per-row max/sum
#pragma unroll
      for (int ti=0;ti<4;++ti)
#pragma unroll
        for (int r=0;r<4;++r){
          int row = 16*ti + 4*q + r;
          float4 s4 = *(const float4*)&stat_sum[row*4];
          mp[bid*128 + 64*p + row] = Mn[ti][r];
          lp[bid*128 + 64*p + row] = s4.x + s4.y + s4.z + s4.w;
        }

    // ---- E @ V : O[pass rows][cols] += E[64][256] * V[256][64]
    const int erb = 32*(w&1), vcb = 32*(w>>1);
#pragma unroll
    for (int ks=0; ks<8; ++ks){
      f16x8 ae[2], bv[2];
#pragma unroll
      for (int a=0;a<2;++a)
        ae[a] = *(const f16x8*)(El + (erb + 16*a + lr)*264 + ks*32 + q*8);
#pragma unroll
      for (int bb=0;bb<2;++bb)
        bv[bb] = *(const f16x8*)(Vb + (size_t)(vcb + 16*bb + lr)*2048 + jg + ks*32 + q*8);
#pragma unroll
      for (int a=0;a<2;++a)
#pragma unroll
        for (int bb=0;bb<2;++bb)
          Oacc[p][a][bb] = __builtin_amdgcn_mfma_f32_16x16x32_f16(ae[a], bv[bb], Oacc[p][a][bb], 0,0,0);
    }
    __syncthreads();                            // B3: El reads done before pass 1
  }

#pragma unroll
  for (int p=0;p<2;++p)
#pragma unroll
    for (int a=0;a<2;++a)
#pragma unroll
      for (int bb=0;bb<2;++bb)
#pragma unroll
        for (int r=0;r<4;++r){
          int row = 64*p + 32*(w&1) + 16*a + 4*q + r;
          int col = 32*(w>>1) + 16*bb + lr;
          Op[((size_t)bid*128 + row)*64 + col] = (f16)Oacc[p][a][bb][r];
        }
}

// ---------------- kernel 3: combine the 8 j-slice partials -----------------
__global__ void k_comb(const f16* __restrict__ Op, const float* __restrict__ mp,
                       const float* __restrict__ lp, float* __restrict__ out){
  const int rb = blockIdx.x;                    // 0..127 = nb*8 + b
  const int b = rb & 7, nb = rb >> 3;
  const int bid0 = rb << 3;
  const int t = threadIdx.x;
  const int row = t >> 1, half = t & 1;

  float m_[8], a_[8];
  float M = -1e30f, den = 0.f;
#pragma unroll
  for (int i=0;i<8;++i){ m_[i] = mp[(bid0+i)*128 + row]; M = fmaxf(M, m_[i]); }
#pragma unroll
  for (int i=0;i<8;++i){ a_[i] = __expf(m_[i] - M); den += a_[i]*lp[(bid0+i)*128 + row]; }
  float inv = 1.0f / den;

#pragma unroll
  for (int g=0;g<4;++g){
    int c0 = half*32 + g*8;
    float o[8] = {};
#pragma unroll
    for (int i=0;i<8;++i){
      f16x8 v = *(const f16x8*)(Op + ((size_t)(bid0+i)*128 + row)*64 + c0);
#pragma unroll
      for (int e=0;e<8;++e) o[e] += a_[i]*(float)v[e];
    }
    float4 o0, o1;
    o0.x=o[0]*inv; o0.y=o[1]*inv; o0.z=o[2]*inv; o0.w=o[3]*inv;
    o1.x=o[4]*inv; o1.y=o[5]*inv; o1.z=o[6]*inv; o1.w=o[7]*inv;
    float* dst = out + ((size_t)b*2048 + nb*128 + row)*64 + c0;
    *(float4*)dst = o0;
    *(float4*)(dst+4) = o1;
  }
}

extern "C" void kernel_launch(void* const* d_in, const int* in_sizes, int n_in,
                              void* d_out, int out_size, void* d_ws, size_t ws_size,
                              hipStream_t stream){
  (void)in_sizes; (void)n_in; (void)out_size; (void)ws_size;
  const float* Q  = (const float*)d_in[0];
  const float* K  = (const float*)d_in[1];
  const float* V  = (const float*)d_in[2];
  const float* Dm = (const float*)d_in[3];
  float* out = (float*)d_out;
  char* ws = (char*)d_ws;
  f16* Ph  = (f16*)ws;                                   // 64 MB
  f16* RhT = (f16*)(ws + (size_t)64*1024*1024);          //  8 MB
  f16* VhT = (f16*)(ws + (size_t)72*1024*1024);          //  2 MB
  f16* Op  = (f16*)(ws + (size_t)74*1024*1024);          // 16 MB (1024*128*64 f16)
  float* mpp = (float*)(ws + (size_t)90*1024*1024);      // 512 KB
  float* lpp = mpp + 1024*128;                           // 512 KB

  k_qk   <<<dim3(3328), 256, 0, stream>>>(Q, K, V, Dm, Ph, RhT, VhT);
  k_attn <<<dim3(1024), 256, 0, stream>>>(Ph, RhT, VhT, Op, mpp, lpp);
  k_comb <<<dim3(128),  256, 0, stream>>>(Op, mpp, lpp, out);
}